// Round 7
// baseline (183.755 us; speedup 1.0000x reference)
//
#include <hip/hip_runtime.h>
#include <hip/hip_bf16.h>

// ODEFunc CNF dynamics, B=1e6 rows, H=64:
//   h1 = elu(W1 z + b1); [h2|u2|v2] = [h1|u|v] W2^T; out01 = W3 elu(h2)+b3;
//   trace = W3[0,:]*(elu'(h2)*u2) + W3[1,:]*(elu'(h2)*v2); out[:,2] = -trace
//
// R7: R6 (MFMA, 16-row tiles/wave) = 72us kernel, MfmaUtil 13%, VALUBusy 56%,
// occupancy 18.5% (2 waves/EU pinned). Bottleneck: VALU dependency stalls
// (exp chains, cvt, MFMA->epilogue) with too little TLP. 4 waves/EU would
// need <=128 unified regs (true demand ~176) -> spill (R1-R5 lesson). So:
// ILP instead - TWO tiles per iteration, independent chains interleaved.
// Peak demand ~240 <= 256 budget: epi consts (48 regs in R6) are no longer
// resident; reloaded per pair-iteration as float4 (L1-hit, hidden by MFMA).
// f2bf via 3-op RNE bit-trick (library __float2bfloat16 is ~5 ops + NaN sel).
// Layout (m120-verified, R6-validated): A-frag = W2 block A[m=lane&15][k=quad*8+jj],
// B-frag = [h|u|v]^T built in-register, D[k][row]: row=lane&15, k=mt*16+quad*4+reg;
// W3-fold = in-lane over 16 k + 2 shfl_xor stages. No LDS.

typedef short bf16x8 __attribute__((ext_vector_type(8)));
typedef float f32x4  __attribute__((ext_vector_type(4)));

// round-to-nearest-even f32 -> bf16, 3 VALU ops (inputs are finite)
static __device__ __forceinline__ short f2bf(float x) {
    unsigned u = __builtin_bit_cast(unsigned, x);
    u = (u + 0x7FFFu + ((u >> 16) & 1u)) >> 16;
    return (short)u;
}

__global__ __launch_bounds__(256) __attribute__((amdgpu_waves_per_eu(2, 2)))
void odefunc_mfma(const float* __restrict__ zin,
                  const float* __restrict__ W1, const float* __restrict__ b1,
                  const float* __restrict__ W2, const float* __restrict__ b2,
                  const float* __restrict__ W3, const float* __restrict__ b3,
                  float* __restrict__ out, int B, int ntiles)
{
    const int lane = threadIdx.x & 63;
    const int quad = lane >> 4;      // 0..3
    const int col  = lane & 15;      // row-within-tile (B/D n-index)

    const int wid    = blockIdx.x * (blockDim.x >> 6) + (threadIdx.x >> 6);
    const int nwaves = gridDim.x * (blockDim.x >> 6);

    // ---- Loop-invariant: W2 as A-operand fragments (4 mtiles x 2 jtiles) ----
    bf16x8 aW2[4][2];
#pragma unroll
    for (int mt = 0; mt < 4; ++mt)
#pragma unroll
        for (int jt = 0; jt < 2; ++jt) {
            const float* p = W2 + (mt * 16 + col) * 64 + jt * 32 + quad * 8;
#pragma unroll
            for (int jj = 0; jj < 8; ++jj) aW2[mt][jt][jj] = f2bf(p[jj]);
        }

    // ---- Loop-invariant: layer-1 constants for this lane's 16 j's ----
    float w0v[2][8], w1v[2][8], b1v[2][8];
#pragma unroll
    for (int jt = 0; jt < 2; ++jt)
#pragma unroll
        for (int jj = 0; jj < 8; ++jj) {
            int j = jt * 32 + quad * 8 + jj;
            w0v[jt][jj] = W1[2 * j];
            w1v[jt][jj] = W1[2 * j + 1];
            b1v[jt][jj] = b1[j];
        }

    const float b30 = b3[0], b31 = b3[1];
    const f32x4 zero4 = {0.f, 0.f, 0.f, 0.f};

    for (int t0 = wid * 2; t0 < ntiles; t0 += 2 * nwaves) {
        const int t1 = t0 + 1;            // store-predicated; compute is safe
        int rowA = t0 * 16 + col;
        int rowB = t1 * 16 + col;
        int rA = rowA < B ? rowA : B - 1;
        int rB = rowB < B ? rowB : B - 1;
        float zA0 = zin[3 * rA + 0], zA1 = zin[3 * rA + 1];
        float zB0 = zin[3 * rB + 0], zB1 = zin[3 * rB + 1];

        // ---- layer 1 (branch-free elu), both tiles interleaved ----
        bf16x8 AhA[2], AuA[2], AvA[2], AhB[2], AuB[2], AvB[2];
#pragma unroll
        for (int jt = 0; jt < 2; ++jt)
#pragma unroll
            for (int jj = 0; jj < 8; ++jj) {
                float w0 = w0v[jt][jj], w1 = w1v[jt][jj], bb = b1v[jt][jj];
                float aA  = fmaf(w0, zA0, fmaf(w1, zA1, bb));
                float aB  = fmaf(w0, zB0, fmaf(w1, zB1, bb));
                float exA = __expf(fminf(aA, 0.f));       // elu'(a)
                float exB = __expf(fminf(aB, 0.f));
                float hA  = fmaxf(aA, 0.f) + (exA - 1.f); // elu(a)
                float hB  = fmaxf(aB, 0.f) + (exB - 1.f);
                AhA[jt][jj] = f2bf(hA);   AhB[jt][jj] = f2bf(hB);
                AuA[jt][jj] = f2bf(exA * w0); AuB[jt][jj] = f2bf(exB * w0);
                AvA[jt][jj] = f2bf(exA * w1); AvB[jt][jj] = f2bf(exB * w1);
            }

        // ---- MFMA: D = W2 * [h|u|v]^T for both tiles (48 MFMAs) ----
        f32x4 aHA[4], aUA[4], aVA[4], aHB[4], aUB[4], aVB[4];
#pragma unroll
        for (int mt = 0; mt < 4; ++mt) {
            aHA[mt] = __builtin_amdgcn_mfma_f32_16x16x32_bf16(aW2[mt][0], AhA[0], zero4, 0, 0, 0);
            aUA[mt] = __builtin_amdgcn_mfma_f32_16x16x32_bf16(aW2[mt][0], AuA[0], zero4, 0, 0, 0);
            aVA[mt] = __builtin_amdgcn_mfma_f32_16x16x32_bf16(aW2[mt][0], AvA[0], zero4, 0, 0, 0);
            aHB[mt] = __builtin_amdgcn_mfma_f32_16x16x32_bf16(aW2[mt][0], AhB[0], zero4, 0, 0, 0);
            aUB[mt] = __builtin_amdgcn_mfma_f32_16x16x32_bf16(aW2[mt][0], AuB[0], zero4, 0, 0, 0);
            aVB[mt] = __builtin_amdgcn_mfma_f32_16x16x32_bf16(aW2[mt][0], AvB[0], zero4, 0, 0, 0);
            aHA[mt] = __builtin_amdgcn_mfma_f32_16x16x32_bf16(aW2[mt][1], AhA[1], aHA[mt], 0, 0, 0);
            aUA[mt] = __builtin_amdgcn_mfma_f32_16x16x32_bf16(aW2[mt][1], AuA[1], aUA[mt], 0, 0, 0);
            aVA[mt] = __builtin_amdgcn_mfma_f32_16x16x32_bf16(aW2[mt][1], AvA[1], aVA[mt], 0, 0, 0);
            aHB[mt] = __builtin_amdgcn_mfma_f32_16x16x32_bf16(aW2[mt][1], AhB[1], aHB[mt], 0, 0, 0);
            aUB[mt] = __builtin_amdgcn_mfma_f32_16x16x32_bf16(aW2[mt][1], AuB[1], aUB[mt], 0, 0, 0);
            aVB[mt] = __builtin_amdgcn_mfma_f32_16x16x32_bf16(aW2[mt][1], AvB[1], aVB[mt], 0, 0, 0);
        }

        // ---- epilogue: elu + W3 fold; consts reloaded (L1-hit float4) ----
        float o0A = 0.f, o1A = 0.f, trA = 0.f;
        float o0B = 0.f, o1B = 0.f, trB = 0.f;
#pragma unroll
        for (int mt = 0; mt < 4; ++mt) {
            int kb = mt * 16 + quad * 4;
            f32x4 b2q  = *(const f32x4*)(b2 + kb);
            f32x4 w30q = *(const f32x4*)(W3 + kb);
            f32x4 w31q = *(const f32x4*)(W3 + 64 + kb);
#pragma unroll
            for (int i = 0; i < 4; ++i) {
                float a2A  = aHA[mt][i] + b2q[i];
                float a2B  = aHB[mt][i] + b2q[i];
                float ex2A = __expf(fminf(a2A, 0.f));
                float ex2B = __expf(fminf(a2B, 0.f));
                float hhA  = fmaxf(a2A, 0.f) + (ex2A - 1.f);
                float hhB  = fmaxf(a2B, 0.f) + (ex2B - 1.f);
                o0A = fmaf(w30q[i], hhA, o0A);  o0B = fmaf(w30q[i], hhB, o0B);
                o1A = fmaf(w31q[i], hhA, o1A);  o1B = fmaf(w31q[i], hhB, o1B);
                trA = fmaf(ex2A, fmaf(w30q[i], aUA[mt][i], w31q[i] * aVA[mt][i]), trA);
                trB = fmaf(ex2B, fmaf(w30q[i], aUB[mt][i], w31q[i] * aVB[mt][i]), trB);
            }
        }

        // ---- cross-quad reduction (k spans quads): 2 butterfly stages ----
        o0A += __shfl_xor(o0A, 16); o0A += __shfl_xor(o0A, 32);
        o1A += __shfl_xor(o1A, 16); o1A += __shfl_xor(o1A, 32);
        trA += __shfl_xor(trA, 16); trA += __shfl_xor(trA, 32);
        o0B += __shfl_xor(o0B, 16); o0B += __shfl_xor(o0B, 32);
        o1B += __shfl_xor(o1B, 16); o1B += __shfl_xor(o1B, 32);
        trB += __shfl_xor(trB, 16); trB += __shfl_xor(trB, 32);

        if (lane < 16 && rowA < B) {
            out[3 * rowA + 0] = o0A + b30;
            out[3 * rowA + 1] = o1A + b31;
            out[3 * rowA + 2] = -trA;
        }
        if (lane < 16 && rowB < B) {     // rowB<B also covers t1>=ntiles
            out[3 * rowB + 0] = o0B + b30;
            out[3 * rowB + 1] = o1B + b31;
            out[3 * rowB + 2] = -trB;
        }
    }
}

extern "C" void kernel_launch(void* const* d_in, const int* in_sizes, int n_in,
                              void* d_out, int out_size, void* d_ws, size_t ws_size,
                              hipStream_t stream) {
    // d_in: 0=t(unused) 1=z_and_logp 2=W1 3=b1 4=W2 5=b2 6=W3 7=b3
    const float* zin = (const float*)d_in[1];
    const float* W1  = (const float*)d_in[2];
    const float* b1  = (const float*)d_in[3];
    const float* W2  = (const float*)d_in[4];
    const float* b2  = (const float*)d_in[5];
    const float* W3  = (const float*)d_in[6];
    const float* b3  = (const float*)d_in[7];
    float* out = (float*)d_out;

    int B = in_sizes[1] / 3;
    int ntiles = (B + 15) / 16;
    int grid = 1024;   // 4096 waves, pair-stride over 62500 tiles
    odefunc_mfma<<<grid, 256, 0, stream>>>(zin, W1, b1, W2, b2, W3, b3,
                                           out, B, ntiles);
}

// Round 8
// 163.156 us; speedup vs baseline: 1.1263x; 1.1263x over previous
//
#include <hip/hip_runtime.h>
#include <hip/hip_bf16.h>

// ODEFunc CNF dynamics, B=1e6 rows, H=64:
//   h1 = elu(W1 z + b1); [h2|u2|v2] = [h1|u|v] W2^T; out01 = W3 elu(h2)+b3;
//   trace = W3[0,:]*(elu'(h2)*u2) + W3[1,:]*(elu'(h2)*v2); out[:,2] = -trace
//
// R8. Register-war history: R6 (all consts persistent, 176 unified) -> 2
// waves/EU, 72us kernel. R7 (2 tiles/iter, ~250 demand) -> scratch spill
// (WRITE 79MB), 121us. This round: PHASE-LOCAL LIVENESS instead of persistence.
//   persistent: aW2 A-fragments (32 regs) + bookkeeping (~10)
//   phase 1 (layer-1): (w0,w1,b1) reloaded per jt-phase from d_ws float4[64]
//     (pre-packed by a tiny pre-kernel; L1-hit dwordx4); peak ~125
//   phase 2 (MFMA): accs 48 (AGPR-native) + B-frags 12; peak ~105
//   phase 3 (epilogue): b2/W3 consts reloaded PER MT (12 regs live); peak ~100
// asm-opaque pointers per tile-iteration defeat LICM re-hoisting (R4-proven).
// Peak ~125 << 170-reg budget of waves_per_eu(3,3): 3 waves/EU, +50% TLP vs R6,
// ~40-reg spill margin. VALU diet: v_cvt_pk_bf16_f32 (gfx950) converts 2
// floats/op, guarded by __has_builtin (fallback: RNE bit-trick).
// MFMA layout (R6-validated): A=W2 block A[m=lane&15][k=quad*8+jj]; B=[h|u|v]^T
// built in-register; D[k][row]: row=lane&15, k=mt*16+quad*4+reg; W3-fold
// in-lane over 16 k + 2 shfl_xor stages. No LDS.

typedef short bf16x8 __attribute__((ext_vector_type(8)));
typedef float f32x4  __attribute__((ext_vector_type(4)));
typedef int   i32x4  __attribute__((ext_vector_type(4)));

#if defined(__has_builtin)
#if __has_builtin(__builtin_amdgcn_cvt_pk_bf16_f32)
#define HAVE_PK_BF16 1
#endif
#endif

#ifdef HAVE_PK_BF16
typedef __bf16 bf16x2_t __attribute__((ext_vector_type(2)));
static __device__ __forceinline__ int f2bf_pk(float a, float b) {
    bf16x2_t r = __builtin_amdgcn_cvt_pk_bf16_f32(a, b);   // lo=a, hi=b
    return __builtin_bit_cast(int, r);
}
#else
static __device__ __forceinline__ int f2bf_pk(float a, float b) {
    unsigned ua = __builtin_bit_cast(unsigned, a);
    unsigned ub = __builtin_bit_cast(unsigned, b);
    ua = (ua + 0x7FFFu + ((ua >> 16) & 1u)) >> 16;
    ub = (ub + 0x7FFFu + ((ub >> 16) & 1u)) & 0xFFFF0000u;
    return (int)(ua | ub);
}
#endif

__global__ __launch_bounds__(256) __attribute__((amdgpu_waves_per_eu(3, 3)))
void odefunc_mfma(const float* __restrict__ zin,
                  const float* __restrict__ wpk,   // packed (w0,w1,b1,0)[64]
                  const float* __restrict__ W2,
                  const float* __restrict__ b2, const float* __restrict__ W3,
                  const float* __restrict__ b3,
                  float* __restrict__ out, int B, int ntiles)
{
    const int lane = threadIdx.x & 63;
    const int quad = lane >> 4;      // 0..3
    const int col  = lane & 15;      // row-within-tile (B/D n-index)

    const int wid    = blockIdx.x * (blockDim.x >> 6) + (threadIdx.x >> 6);
    const int nwaves = gridDim.x * (blockDim.x >> 6);

    // ---- Persistent: W2 as A-operand fragments (4 mtiles x 2 jtiles) ----
    bf16x8 aW2[4][2];
#pragma unroll
    for (int mt = 0; mt < 4; ++mt)
#pragma unroll
        for (int jt = 0; jt < 2; ++jt) {
            const float* p = W2 + (mt * 16 + col) * 64 + jt * 32 + quad * 8;
            i32x4 w;
#pragma unroll
            for (int p2 = 0; p2 < 4; ++p2)
                w[p2] = f2bf_pk(p[2 * p2], p[2 * p2 + 1]);
            aW2[mt][jt] = __builtin_bit_cast(bf16x8, w);
        }

    const float b30 = b3[0], b31 = b3[1];
    const f32x4 zero4 = {0.f, 0.f, 0.f, 0.f};

    for (int t = wid; t < ntiles; t += nwaves) {
        int row = t * 16 + col;
        int rl = row < B ? row : B - 1;
        float z0 = zin[3 * rl + 0];
        float z1 = zin[3 * rl + 1];

        // Opaque per-iteration pointers: the reloads below must NOT be
        // LICM-hoisted back into persistent registers.
        const float* wp  = wpk;
        const float* b2p = b2;
        const float* w3p = W3;
        asm volatile("" : "+s"(wp), "+s"(b2p), "+s"(w3p));

        f32x4 accH[4], accU[4], accV[4];

#pragma unroll
        for (int jt = 0; jt < 2; ++jt) {
            // ---- phase 1: layer-1 (branch-free elu) -> B-fragments ----
            i32x4 Ah, Au, Av;
#pragma unroll
            for (int p2 = 0; p2 < 4; ++p2) {
                int j0 = jt * 32 + quad * 8 + 2 * p2;
                f32x4 c0 = *(const f32x4*)(wp + 4 * j0);       // w0,w1,b1,_
                f32x4 c1 = *(const f32x4*)(wp + 4 * j0 + 4);
                float a0 = fmaf(c0.x, z0, fmaf(c0.y, z1, c0.z));
                float a1 = fmaf(c1.x, z0, fmaf(c1.y, z1, c1.z));
                float e0 = __expf(fminf(a0, 0.f));             // elu'
                float e1 = __expf(fminf(a1, 0.f));
                float h0 = fmaxf(a0, 0.f) + (e0 - 1.f);        // elu
                float h1 = fmaxf(a1, 0.f) + (e1 - 1.f);
                Ah[p2] = f2bf_pk(h0, h1);
                Au[p2] = f2bf_pk(e0 * c0.x, e1 * c1.x);
                Av[p2] = f2bf_pk(e0 * c0.y, e1 * c1.y);
            }
            bf16x8 bh = __builtin_bit_cast(bf16x8, Ah);
            bf16x8 bu = __builtin_bit_cast(bf16x8, Au);
            bf16x8 bv = __builtin_bit_cast(bf16x8, Av);

            // ---- phase 2: MFMA k-step for all 4 mtiles ----
#pragma unroll
            for (int mt = 0; mt < 4; ++mt) {
                accH[mt] = __builtin_amdgcn_mfma_f32_16x16x32_bf16(
                    aW2[mt][jt], bh, jt == 0 ? zero4 : accH[mt], 0, 0, 0);
                accU[mt] = __builtin_amdgcn_mfma_f32_16x16x32_bf16(
                    aW2[mt][jt], bu, jt == 0 ? zero4 : accU[mt], 0, 0, 0);
                accV[mt] = __builtin_amdgcn_mfma_f32_16x16x32_bf16(
                    aW2[mt][jt], bv, jt == 0 ? zero4 : accV[mt], 0, 0, 0);
            }
        }

        // ---- phase 3: elu + W3 fold; consts reloaded per mt (12 live) ----
        float o0 = 0.f, o1 = 0.f, trc = 0.f;
#pragma unroll
        for (int mt = 0; mt < 4; ++mt) {
            int kb = mt * 16 + quad * 4;
            f32x4 b2q  = *(const f32x4*)(b2p + kb);
            f32x4 w30q = *(const f32x4*)(w3p + kb);
            f32x4 w31q = *(const f32x4*)(w3p + 64 + kb);
#pragma unroll
            for (int i = 0; i < 4; ++i) {
                float a2  = accH[mt][i] + b2q[i];
                float ex2 = __expf(fminf(a2, 0.f));
                float hh  = fmaxf(a2, 0.f) + (ex2 - 1.f);
                o0  = fmaf(w30q[i], hh, o0);
                o1  = fmaf(w31q[i], hh, o1);
                trc = fmaf(ex2, fmaf(w30q[i], accU[mt][i],
                                     w31q[i] * accV[mt][i]), trc);
            }
        }

        // ---- cross-quad reduction (k spans quads): 2 butterfly stages ----
        o0  += __shfl_xor(o0, 16);  o0  += __shfl_xor(o0, 32);
        o1  += __shfl_xor(o1, 16);  o1  += __shfl_xor(o1, 32);
        trc += __shfl_xor(trc, 16); trc += __shfl_xor(trc, 32);

        if (lane < 16 && row < B) {
            out[3 * row + 0] = o0 + b30;
            out[3 * row + 1] = o1 + b31;
            out[3 * row + 2] = -trc;
        }
    }
}

// Pre-kernel: pack (W1[j,0], W1[j,1], b1[j], 0) into float4[64] in d_ws.
__global__ void pack_w1(const float* __restrict__ W1,
                        const float* __restrict__ b1,
                        float* __restrict__ ws)
{
    int j = threadIdx.x;
    if (j < 64) {
        ws[4 * j + 0] = W1[2 * j + 0];
        ws[4 * j + 1] = W1[2 * j + 1];
        ws[4 * j + 2] = b1[j];
        ws[4 * j + 3] = 0.f;
    }
}

extern "C" void kernel_launch(void* const* d_in, const int* in_sizes, int n_in,
                              void* d_out, int out_size, void* d_ws, size_t ws_size,
                              hipStream_t stream) {
    // d_in: 0=t(unused) 1=z_and_logp 2=W1 3=b1 4=W2 5=b2 6=W3 7=b3
    const float* zin = (const float*)d_in[1];
    const float* W1  = (const float*)d_in[2];
    const float* b1  = (const float*)d_in[3];
    const float* W2  = (const float*)d_in[4];
    const float* b2  = (const float*)d_in[5];
    const float* W3  = (const float*)d_in[6];
    const float* b3  = (const float*)d_in[7];
    float* out = (float*)d_out;
    float* wsf = (float*)d_ws;

    int B = in_sizes[1] / 3;
    int ntiles = (B + 15) / 16;

    pack_w1<<<1, 64, 0, stream>>>(W1, b1, wsf);
    // 768 blocks x 4 waves = 3072 waves = exactly 3/EU x 4 EU x 256 CU resident
    odefunc_mfma<<<768, 256, 0, stream>>>(zin, wsf, W2, b2, W3, b3,
                                          out, B, ntiles);
}

// Round 9
// 153.163 us; speedup vs baseline: 1.1997x; 1.0652x over previous
//
#include <hip/hip_runtime.h>
#include <hip/hip_bf16.h>

// ODEFunc CNF dynamics, B=1e6 rows, H=64:
//   h1 = elu(W1 z + b1); [h2|u2|v2] = [h1|u|v] W2^T; out01 = W3 elu(h2)+b3;
//   trace = W3[0,:]*(elu'(h2)*u2) + W3[1,:]*(elu'(h2)*v2); out[:,2] = -trace
//
// R9 = R6 (best: 72us kernel, persistent consts, 2 waves/EU) + two fixes:
//  (1) SOFTWARE-PIPELINED z: the only long-latency op per tile was the z
//      global load sitting directly before phase-1 (L2 ~200-900cyc, only 2
//      waves/EU to hide it -> VALUBusy 56%). Prefetch z(t+nwaves) during
//      tile t's compute; consume next iteration. R8 taught: constants must
//      stay PERSISTENT (lane-dependent reload addresses = per-lane global
//      loads on the critical path -> 105us regression).
//  (2) v_cvt_pk_bf16_f32: 2 floats/op for all 48 f32->bf16 per tile
//      (~144 ops -> ~24).
// MFMA layout (R6-validated): A=W2 block A[m=lane&15][k=quad*8+jj]; B=[h|u|v]^T
// built in-register; D[k][row]: row=lane&15, k=mt*16+quad*4+reg; W3-fold
// in-lane over 16 k + 2 shfl_xor stages. No LDS.
// Registers: aW2 32 + layer1 consts 48 + epi consts 48 + acc 48(AGPR) + temps
// ~= 200 unified < 256 budget (waves_per_eu(2,2)).

typedef short bf16x8 __attribute__((ext_vector_type(8)));
typedef float f32x4  __attribute__((ext_vector_type(4)));
typedef int   i32x4  __attribute__((ext_vector_type(4)));

#if defined(__has_builtin)
#if __has_builtin(__builtin_amdgcn_cvt_pk_bf16_f32)
#define HAVE_PK_BF16 1
#endif
#endif

#ifdef HAVE_PK_BF16
typedef __bf16 bf16x2_t __attribute__((ext_vector_type(2)));
static __device__ __forceinline__ int f2bf_pk(float a, float b) {
    bf16x2_t r = __builtin_amdgcn_cvt_pk_bf16_f32(a, b);   // lo=a, hi=b
    return __builtin_bit_cast(int, r);
}
#else
static __device__ __forceinline__ int f2bf_pk(float a, float b) {
    unsigned ua = __builtin_bit_cast(unsigned, a);
    unsigned ub = __builtin_bit_cast(unsigned, b);
    ua = (ua + 0x7FFFu + ((ua >> 16) & 1u)) >> 16;
    ub = (ub + 0x7FFFu + ((ub >> 16) & 1u)) & 0xFFFF0000u;
    return (int)(ua | ub);
}
#endif

__global__ __launch_bounds__(256) __attribute__((amdgpu_waves_per_eu(2, 2)))
void odefunc_mfma(const float* __restrict__ zin,
                  const float* __restrict__ W1, const float* __restrict__ b1,
                  const float* __restrict__ W2, const float* __restrict__ b2,
                  const float* __restrict__ W3, const float* __restrict__ b3,
                  float* __restrict__ out, int B, int ntiles)
{
    const int lane = threadIdx.x & 63;
    const int quad = lane >> 4;      // 0..3
    const int col  = lane & 15;      // row-within-tile (B/D n-index)

    const int wid    = blockIdx.x * (blockDim.x >> 6) + (threadIdx.x >> 6);
    const int nwaves = gridDim.x * (blockDim.x >> 6);

    // ---- Persistent: W2 as A-operand fragments (4 mtiles x 2 jtiles) ----
    bf16x8 aW2[4][2];
#pragma unroll
    for (int mt = 0; mt < 4; ++mt)
#pragma unroll
        for (int jt = 0; jt < 2; ++jt) {
            const float* p = W2 + (mt * 16 + col) * 64 + jt * 32 + quad * 8;
            i32x4 w;
#pragma unroll
            for (int p2 = 0; p2 < 4; ++p2)
                w[p2] = f2bf_pk(p[2 * p2], p[2 * p2 + 1]);
            aW2[mt][jt] = __builtin_bit_cast(bf16x8, w);
        }

    // ---- Persistent: layer-1 constants for this lane's 16 j's ----
    float w0v[2][8], w1v[2][8], b1v[2][8];
#pragma unroll
    for (int jt = 0; jt < 2; ++jt)
#pragma unroll
        for (int jj = 0; jj < 8; ++jj) {
            int j = jt * 32 + quad * 8 + jj;
            w0v[jt][jj] = W1[2 * j];
            w1v[jt][jj] = W1[2 * j + 1];
            b1v[jt][jj] = b1[j];
        }

    // ---- Persistent: epilogue constants for this lane's 16 k's ----
    float b2v[4][4], w30v[4][4], w31v[4][4];
#pragma unroll
    for (int mt = 0; mt < 4; ++mt)
#pragma unroll
        for (int i = 0; i < 4; ++i) {
            int k = mt * 16 + quad * 4 + i;
            b2v[mt][i]  = b2[k];
            w30v[mt][i] = W3[k];        // W3[0,k]
            w31v[mt][i] = W3[64 + k];   // W3[1,k]
        }
    const float b30 = b3[0], b31 = b3[1];
    const f32x4 zero4 = {0.f, 0.f, 0.f, 0.f};

    // ---- Software pipeline: prefetch z for the first tile ----
    int t = wid;
    float z0n = 0.f, z1n = 0.f;
    if (t < ntiles) {
        int row = t * 16 + col;
        int rl = row < B ? row : B - 1;
        z0n = zin[3 * rl + 0];
        z1n = zin[3 * rl + 1];
    }

    for (; t < ntiles; t += nwaves) {
        int row = t * 16 + col;
        float z0 = z0n, z1 = z1n;

        // Prefetch next tile's z NOW; latency hides under this tile's compute.
        {
            int tn = t + nwaves;
            int rown = tn < ntiles ? tn * 16 + col : row;
            int rln = rown < B ? rown : B - 1;
            z0n = zin[3 * rln + 0];
            z1n = zin[3 * rln + 1];
        }

        // ---- phase 1: layer-1 (branch-free elu) -> B-fragments ----
        bf16x8 Ah[2], Au[2], Av[2];
#pragma unroll
        for (int jt = 0; jt < 2; ++jt) {
            i32x4 ah, au, av;
#pragma unroll
            for (int p2 = 0; p2 < 4; ++p2) {
                int j0 = 2 * p2, j1 = 2 * p2 + 1;
                float wa0 = w0v[jt][j0], wb0 = w1v[jt][j0];
                float wa1 = w0v[jt][j1], wb1 = w1v[jt][j1];
                float a0 = fmaf(wa0, z0, fmaf(wb0, z1, b1v[jt][j0]));
                float a1 = fmaf(wa1, z0, fmaf(wb1, z1, b1v[jt][j1]));
                float e0 = __expf(fminf(a0, 0.f));             // elu'
                float e1 = __expf(fminf(a1, 0.f));
                float h0 = fmaxf(a0, 0.f) + (e0 - 1.f);        // elu
                float h1 = fmaxf(a1, 0.f) + (e1 - 1.f);
                ah[p2] = f2bf_pk(h0, h1);
                au[p2] = f2bf_pk(e0 * wa0, e1 * wa1);
                av[p2] = f2bf_pk(e0 * wb0, e1 * wb1);
            }
            Ah[jt] = __builtin_bit_cast(bf16x8, ah);
            Au[jt] = __builtin_bit_cast(bf16x8, au);
            Av[jt] = __builtin_bit_cast(bf16x8, av);
        }

        // ---- phase 2: MFMA, K=64 as 2 chained k-steps, 4 mtiles ----
        f32x4 accH[4], accU[4], accV[4];
#pragma unroll
        for (int mt = 0; mt < 4; ++mt) {
            accH[mt] = __builtin_amdgcn_mfma_f32_16x16x32_bf16(aW2[mt][0], Ah[0], zero4, 0, 0, 0);
            accU[mt] = __builtin_amdgcn_mfma_f32_16x16x32_bf16(aW2[mt][0], Au[0], zero4, 0, 0, 0);
            accV[mt] = __builtin_amdgcn_mfma_f32_16x16x32_bf16(aW2[mt][0], Av[0], zero4, 0, 0, 0);
        }
#pragma unroll
        for (int mt = 0; mt < 4; ++mt) {
            accH[mt] = __builtin_amdgcn_mfma_f32_16x16x32_bf16(aW2[mt][1], Ah[1], accH[mt], 0, 0, 0);
            accU[mt] = __builtin_amdgcn_mfma_f32_16x16x32_bf16(aW2[mt][1], Au[1], accU[mt], 0, 0, 0);
            accV[mt] = __builtin_amdgcn_mfma_f32_16x16x32_bf16(aW2[mt][1], Av[1], accV[mt], 0, 0, 0);
        }

        // ---- phase 3: elu + W3 fold, in-lane over this lane's 16 k's ----
        float o0 = 0.f, o1 = 0.f, trc = 0.f;
#pragma unroll
        for (int mt = 0; mt < 4; ++mt)
#pragma unroll
            for (int i = 0; i < 4; ++i) {
                float a2  = accH[mt][i] + b2v[mt][i];
                float ex2 = __expf(fminf(a2, 0.f));
                float hh  = fmaxf(a2, 0.f) + (ex2 - 1.f);
                o0  = fmaf(w30v[mt][i], hh, o0);
                o1  = fmaf(w31v[mt][i], hh, o1);
                trc = fmaf(ex2, fmaf(w30v[mt][i], accU[mt][i],
                                     w31v[mt][i] * accV[mt][i]), trc);
            }

        // ---- cross-quad reduction (k spans quads): 2 butterfly stages ----
        o0  += __shfl_xor(o0, 16);  o0  += __shfl_xor(o0, 32);
        o1  += __shfl_xor(o1, 16);  o1  += __shfl_xor(o1, 32);
        trc += __shfl_xor(trc, 16); trc += __shfl_xor(trc, 32);

        if (lane < 16 && row < B) {
            out[3 * row + 0] = o0 + b30;
            out[3 * row + 1] = o1 + b31;
            out[3 * row + 2] = -trc;
        }
    }
}

extern "C" void kernel_launch(void* const* d_in, const int* in_sizes, int n_in,
                              void* d_out, int out_size, void* d_ws, size_t ws_size,
                              hipStream_t stream) {
    // d_in: 0=t(unused) 1=z_and_logp 2=W1 3=b1 4=W2 5=b2 6=W3 7=b3
    const float* zin = (const float*)d_in[1];
    const float* W1  = (const float*)d_in[2];
    const float* b1  = (const float*)d_in[3];
    const float* W2  = (const float*)d_in[4];
    const float* b2  = (const float*)d_in[5];
    const float* W3  = (const float*)d_in[6];
    const float* b3  = (const float*)d_in[7];
    float* out = (float*)d_out;

    int B = in_sizes[1] / 3;
    int ntiles = (B + 15) / 16;
    int grid = 1024;   // 4096 waves, grid-stride over 62500 tiles
    odefunc_mfma<<<grid, 256, 0, stream>>>(zin, W1, b1, W2, b2, W3, b3,
                                           out, B, ntiles);
}